// Round 4
// baseline (420.190 us; speedup 1.0000x reference)
//
#include <hip/hip_runtime.h>

// LIF bitshift-decay scan: B=32, T=1024, N=1024, n_syn=2. fp32, bit-exact.
//
// R1/R2/R3 (three disjoint memory engines) all ~393-401 us, and the kernel
// never shows in rocprof top-5 (1 GiB harness memsets @161us do) => timed
// figure carries ~280 us of fixed harness restore work; true kernel ~110 us
// = ~3.5 TB/s. Shared limiter across all three: 256 B-granular wave accesses
// (4 B/lane) at 4-8 KiB strides -> poor DRAM burst locality.
//
// R4: 16 B/lane. Each lane runs 4 adjacent scans (n = 4*lane..+3) with
// float4 loads/stores -> every wave access is 1 KiB contiguous. 128 one-wave
// blocks (32 batches x 4 neuron-quarters). 4-way ILP on the scan chain.
// Register double-buffer, 8-step chunks (16 float4 loads in flight).
//
// Numerics: per-scan expression order identical to the verified-bit-exact R1:
//   i = (i - i*sd) + x;  v = (v - v*md) + (i0 + i1);  spike-subtract 1.0.

#define TT 1024
#define NN 1024
#define BB 32
#define UU 8   // time-steps per chunk

__device__ __forceinline__ float lif_step(float x0, float x1,
                                          float& i0, float& i1, float& v) {
    const float SD0 = 0.25f;   // 2^-2 (tau_syn=5)
    const float SD1 = 0.5f;    // 2^-1 (tau_syn=2)
    const float MD  = 0.125f;  // 2^-3 (tau_mem=10)
    i0 = (i0 - i0 * SD0) + x0;
    i1 = (i1 - i1 * SD1) + x1;
    float vd = v - v * MD;
    v = vd + (i0 + i1);
    float s_ = (v >= 1.0f) ? 1.0f : 0.0f;
    v -= s_;                   // membrane-subtract reset (thr = 1.0)
    return s_;
}

__global__ __launch_bounds__(64, 1)
void lif_scan_kernel(const float* __restrict__ in, float* __restrict__ out) {
    const int lane = threadIdx.x;
    const int b = blockIdx.x >> 2;          // 32 batches
    const int q = blockIdx.x & 3;           // 4 quarters of 256 neurons
    const int nv = (q << 6) + lane;         // float4 index in a 1024-float row

    // row (t,s) of batch b starts at float offset ((t*2+s)*1024); in float4
    // units: (t*2+s)*256. This wave's slice: + nv  (1 KiB contiguous/wave).
    const float4* gin  = (const float4*)(in  + (size_t)b * TT * 2 * NN) + nv;
    float4*       gout = (float4*)      (out + (size_t)b * TT * NN)     + nv;

    float i0[4] = {0,0,0,0}, i1[4] = {0,0,0,0}, vm[4] = {0,0,0,0};

    // prologue: load chunk 0
    float4 x0[UU], x1[UU];
#pragma unroll
    for (int j = 0; j < UU; ++j) {
        x0[j] = gin[j * 512];          // syn 0: t*512
        x1[j] = gin[j * 512 + 256];    // syn 1: t*512 + 256
    }

    for (int tc = 0; tc < TT - UU; tc += UU) {
        // prefetch chunk k+1
        float4 y0[UU], y1[UU];
        const float4* pn = gin + (size_t)(tc + UU) * 512;
#pragma unroll
        for (int j = 0; j < UU; ++j) {
            y0[j] = pn[j * 512];
            y1[j] = pn[j * 512 + 256];
        }
        // compute chunk k, store spikes as 1 KiB float4 rows
        float4* po = gout + (size_t)tc * 256;
#pragma unroll
        for (int j = 0; j < UU; ++j) {
            float4 a = x0[j], c = x1[j], sp;
            sp.x = lif_step(a.x, c.x, i0[0], i1[0], vm[0]);
            sp.y = lif_step(a.y, c.y, i0[1], i1[1], vm[1]);
            sp.z = lif_step(a.z, c.z, i0[2], i1[2], vm[2]);
            sp.w = lif_step(a.w, c.w, i0[3], i1[3], vm[3]);
            po[j * 256] = sp;
        }
#pragma unroll
        for (int j = 0; j < UU; ++j) { x0[j] = y0[j]; x1[j] = y1[j]; }
    }

    // epilogue: last chunk
    {
        float4* po = gout + (size_t)(TT - UU) * 256;
#pragma unroll
        for (int j = 0; j < UU; ++j) {
            float4 a = x0[j], c = x1[j], sp;
            sp.x = lif_step(a.x, c.x, i0[0], i1[0], vm[0]);
            sp.y = lif_step(a.y, c.y, i0[1], i1[1], vm[1]);
            sp.z = lif_step(a.z, c.z, i0[2], i1[2], vm[2]);
            sp.w = lif_step(a.w, c.w, i0[3], i1[3], vm[3]);
            po[j * 256] = sp;
        }
    }
}

extern "C" void kernel_launch(void* const* d_in, const int* in_sizes, int n_in,
                              void* d_out, int out_size, void* d_ws, size_t ws_size,
                              hipStream_t stream) {
    const float* in = (const float*)d_in[0];
    float* out = (float*)d_out;
    dim3 grid(BB * 4);   // 128 one-wave blocks: (batch, neuron-quarter)
    dim3 block(64);
    hipLaunchKernelGGL(lif_scan_kernel, grid, block, 0, stream, in, out);
}